// Round 11
// baseline (282.168 us; speedup 1.0000x reference)
//
#include <hip/hip_runtime.h>

typedef float f32x4 __attribute__((ext_vector_type(4)));
typedef short bf16x8 __attribute__((ext_vector_type(8)));

// ---- workspace layout (bytes) ----
// B1s: [16 kb][528 cols][128 B]  (bf16, chunk-swizzled; cols 512-519 router, 520-527 zero)
// W2s: [1024 cols][640 B]        (bf16, chunk-swizzled; rows 256-263 = b2, 264-319 zero)
// ACT: [32768 rows][640 B]       (bf16, chunk-swizzled; k 256-263 = p, 264-319 zero)
#define B1S_KBSZ 67584
#define W2S_OFF  1081344
#define ACT_OFF  1736704
// total ws required: 22,708,224 bytes

__device__ __forceinline__ unsigned short f2bf(float f) {
  unsigned int u = __float_as_uint(f);
  return (unsigned short)((u + 0x7FFFu + ((u >> 16) & 1u)) >> 16);
}
__device__ __forceinline__ unsigned int pack2(float a, float b) {
  return (unsigned int)f2bf(a) | ((unsigned int)f2bf(b) << 16);
}
__device__ __forceinline__ unsigned int cvtpk(float a, float b) {
  unsigned int r;
  asm("v_cvt_pk_bf16_f32 %0, %1, %2" : "=v"(r) : "v"(a), "v"(b));
  return r;
}
__device__ __forceinline__ bf16x8 cvt8(f32x4 lo, f32x4 hi) {
  union { uint4 u; bf16x8 b; } r;
  r.u.x = cvtpk(lo.x, lo.y); r.u.y = cvtpk(lo.z, lo.w);
  r.u.z = cvtpk(hi.x, hi.y); r.u.w = cvtpk(hi.z, hi.w);
  return r.b;
}

// ---------------- prep: pack [W1|Wr|0] -> B1s ; [W2;b2;0] -> W2s ----------------
__global__ __launch_bounds__(256) void prep_all(const float* __restrict__ W1,
                                                const float* __restrict__ Wr,
                                                const float* __restrict__ W2,
                                                const float* __restrict__ b2,
                                                unsigned char* __restrict__ B1s,
                                                unsigned char* __restrict__ W2s) {
  if (blockIdx.x < 264) {
    int t = blockIdx.x * 256 + threadIdx.x;
    int c   = t & 7;
    int col = (t >> 3) % 528;
    int kb  = (t >> 3) / 528;
    int e   = col >> 6;
    int hh  = col & 63;
    float v[8];
    #pragma unroll
    for (int jj = 0; jj < 8; ++jj) {
      int k = kb * 64 + c * 8 + jj;
      float f;
      if (col < 512)      f = W1[(e * 1024 + k) * 64 + hh];   // W1[e][k][hh]
      else if (col < 520) f = Wr[k * 8 + (col - 512)];        // Wr[k][e]
      else                f = 0.0f;
      v[jj] = f;
    }
    *(uint4*)(B1s + kb * B1S_KBSZ + col * 128 + ((c ^ (col & 7)) * 16)) =
        make_uint4(pack2(v[0], v[1]), pack2(v[2], v[3]), pack2(v[4], v[5]), pack2(v[6], v[7]));
  } else {
    int t = (blockIdx.x - 264) * 256 + threadIdx.x;
    int cj  = t % 40;
    int col = t / 40;
    float v[8];
    #pragma unroll
    for (int jj = 0; jj < 8; ++jj) {
      int k = cj * 8 + jj;
      float f;
      if (k < 256)      f = W2[k * 1024 + col];          // W2[e][h][c], k=e*32+h
      else if (k < 264) f = b2[(k - 256) * 1024 + col];  // b2[e][c]
      else              f = 0.0f;
      v[jj] = f;
    }
    int dstc = (cj & ~7) | ((cj & 7) ^ (col & 7));
    *(uint4*)(W2s + col * 640 + dstc * 16) =
        make_uint4(pack2(v[0], v[1]), pack2(v[2], v[3]), pack2(v[4], v[5]), pack2(v[6], v[7]));
  }
}

// ---------------- kernel 1: 64 rows x 4 experts/block, zero-LDS K-loop, reg-pipelined ----------------
// grid 1024 = 512 M-tiles x 2 halves; block 256 = 4 waves; wave = 1 expert (64x64)
// A (f32) issued one full ks ahead; cvt8 off critical path; B one half-step ahead.
__global__ __launch_bounds__(256, 2) void moe_gemm1(
    const float* __restrict__ x, const float* __restrict__ br, const float* __restrict__ b1,
    const unsigned char* __restrict__ B1s, unsigned char* __restrict__ ACT) {
  __shared__ __align__(16) unsigned char smem[30720];
  // hb u16[64][136] @0 (17408) ; logitP f32[4][64][8] @17408 ; logit f32[64][8] @25600 ;
  // pb f32[64][8] @27648

  const int tid  = threadIdx.x;
  const int lane = tid & 63;
  const int w    = tid >> 6;   // wave 0..3
  const int f15  = lane & 15;
  const int fhi  = lane >> 4;
  const int k7   = f15 & 7;

  const int wid  = ((blockIdx.x & 7) << 7) + (blockIdx.x >> 3);  // XCD-chunked, 1024=8*128
  const int mt   = wid >> 1;
  const int half = wid & 1;
  const int m0   = mt << 6;
  const int e    = half * 4 + w;

  f32x4 acc[4][4];   // [mf][nf]
  f32x4 accR[4];     // router partial (this wave's 4 ks)
  #pragma unroll
  for (int a = 0; a < 4; ++a) {
    #pragma unroll
    for (int b = 0; b < 4; ++b) acc[a][b] = f32x4{0.f, 0.f, 0.f, 0.f};
    accR[a] = f32x4{0.f, 0.f, 0.f, 0.f};
  }

  const float* xA = x + (size_t)(m0 + f15) * 1024 + fhi * 8;
  const unsigned char* bp  = B1s + (size_t)(e * 64 + f15) * 128;
  const unsigned char* brt = B1s + (size_t)(512 + f15) * 128;
  const int ch0 = ((fhi)     ^ k7) << 4;
  const int ch1 = ((4 + fhi) ^ k7) << 4;

  bf16x8 af[2][8];   // [ks&1][ksub*4+mf] — converted A frags, filled one ks ahead
  bf16x8 bb0[4], bb1[4];
  f32x4 t[8];

  // ---- prologue: A(ks0, both halves) + B(ks0, ksub0) ----
  #pragma unroll
  for (int mf = 0; mf < 4; ++mf) {
    const float* s_ = xA + (size_t)mf * 16384;
    t[mf * 2] = *(const f32x4*)s_; t[mf * 2 + 1] = *(const f32x4*)(s_ + 4);
  }
  #pragma unroll
  for (int i = 0; i < 4; ++i) bb0[i] = *(const bf16x8*)(bp + i * 2048 + ch0);
  #pragma unroll
  for (int mf = 0; mf < 4; ++mf) af[0][mf] = cvt8(t[mf * 2], t[mf * 2 + 1]);
  #pragma unroll
  for (int mf = 0; mf < 4; ++mf) {
    const float* s_ = xA + (size_t)mf * 16384 + 32;
    t[mf * 2] = *(const f32x4*)s_; t[mf * 2 + 1] = *(const f32x4*)(s_ + 4);
  }
  #pragma unroll
  for (int mf = 0; mf < 4; ++mf) af[0][4 + mf] = cvt8(t[mf * 2], t[mf * 2 + 1]);

  #pragma unroll
  for (int ks = 0; ks < 16; ++ks) {
    const int cur = ks & 1, nxt = cur ^ 1;
    const size_t kso = (size_t)ks * B1S_KBSZ;
    const size_t ksn = kso + B1S_KBSZ;
    const bool doR = ((ks >> 2) == w);

    // issue: B(ks, ksub1) and A(ks+1, half0)
    #pragma unroll
    for (int i = 0; i < 4; ++i) bb1[i] = *(const bf16x8*)(bp + kso + i * 2048 + ch1);
    if (ks < 15) {
      #pragma unroll
      for (int mf = 0; mf < 4; ++mf) {
        const float* s_ = xA + (size_t)mf * 16384 + (ks + 1) * 64;
        t[mf * 2] = *(const f32x4*)s_; t[mf * 2 + 1] = *(const f32x4*)(s_ + 4);
      }
    }
    bf16x8 r0, r1;
    if (doR) r0 = *(const bf16x8*)(brt + kso + ch0);

    // MFMA ksub0 (consumes af[cur][0..3], bb0 — both loaded >= half iter ago)
    #pragma unroll
    for (int i = 0; i < 4; ++i)
      #pragma unroll
      for (int mf = 0; mf < 4; ++mf)
        acc[mf][i] = __builtin_amdgcn_mfma_f32_16x16x32_bf16(af[cur][mf], bb0[i], acc[mf][i], 0, 0, 0);
    if (doR) {
      #pragma unroll
      for (int mf = 0; mf < 4; ++mf)
        accR[mf] = __builtin_amdgcn_mfma_f32_16x16x32_bf16(af[cur][mf], r0, accR[mf], 0, 0, 0);
    }

    // cvt A(ks+1, half0); issue B(ks+1, ksub0) and A(ks+1, half1)
    if (ks < 15) {
      #pragma unroll
      for (int mf = 0; mf < 4; ++mf) af[nxt][mf] = cvt8(t[mf * 2], t[mf * 2 + 1]);
      #pragma unroll
      for (int i = 0; i < 4; ++i) bb0[i] = *(const bf16x8*)(bp + ksn + i * 2048 + ch0);
      #pragma unroll
      for (int mf = 0; mf < 4; ++mf) {
        const float* s_ = xA + (size_t)mf * 16384 + (ks + 1) * 64 + 32;
        t[mf * 2] = *(const f32x4*)s_; t[mf * 2 + 1] = *(const f32x4*)(s_ + 4);
      }
    }
    if (doR) r1 = *(const bf16x8*)(brt + kso + ch1);

    // MFMA ksub1
    #pragma unroll
    for (int i = 0; i < 4; ++i)
      #pragma unroll
      for (int mf = 0; mf < 4; ++mf)
        acc[mf][i] = __builtin_amdgcn_mfma_f32_16x16x32_bf16(af[cur][4 + mf], bb1[i], acc[mf][i], 0, 0, 0);
    if (doR) {
      #pragma unroll
      for (int mf = 0; mf < 4; ++mf)
        accR[mf] = __builtin_amdgcn_mfma_f32_16x16x32_bf16(af[cur][4 + mf], r1, accR[mf], 0, 0, 0);
    }

    // cvt A(ks+1, half1)
    if (ks < 15) {
      #pragma unroll
      for (int mf = 0; mf < 4; ++mf) af[nxt][4 + mf] = cvt8(t[mf * 2], t[mf * 2 + 1]);
    }
    if ((ks & 3) == 3) __syncthreads();  // keep waves converged for L1/L2 A-sharing
  }

  unsigned short* hb = (unsigned short*)smem;      // [64][136]: cols 0-127 act, 128-135 p(bf16)
  float* logitP = (float*)(smem + 17408);          // [4][64][8]
  float* logit  = (float*)(smem + 25600);          // [64][8]
  float* pb     = (float*)(smem + 27648);          // [64][8]

  if (f15 < 8) {  // router partials
    #pragma unroll
    for (int mf = 0; mf < 4; ++mf)
      #pragma unroll
      for (int r = 0; r < 4; ++r)
        logitP[(w * 64 + mf * 16 + fhi * 4 + r) * 8 + f15] = accR[mf][r];
  }
  __syncthreads();
  {  // reduce partials + br
    int row = tid >> 2, ep = tid & 3;
    #pragma unroll
    for (int j = 0; j < 2; ++j) {
      int ee = ep * 2 + j;
      float s = logitP[row * 8 + ee] + logitP[(64 + row) * 8 + ee] +
                logitP[(128 + row) * 8 + ee] + logitP[(192 + row) * 8 + ee];
      logit[row * 8 + ee] = s + br[ee];
    }
  }
  __syncthreads();
  if (tid < 64) {  // per-row softmax
    int row = tid;
    const float* lg = logit + row * 8;
    float l0 = lg[0], l1 = lg[1], l2 = lg[2], l3 = lg[3];
    float l4 = lg[4], l5 = lg[5], l6 = lg[6], l7 = lg[7];
    float mx = fmaxf(fmaxf(fmaxf(l0, l1), fmaxf(l2, l3)),
                     fmaxf(fmaxf(l4, l5), fmaxf(l6, l7)));
    float e0 = __expf(l0 - mx), e1 = __expf(l1 - mx), e2 = __expf(l2 - mx), e3 = __expf(l3 - mx);
    float e4 = __expf(l4 - mx), e5 = __expf(l5 - mx), e6 = __expf(l6 - mx), e7 = __expf(l7 - mx);
    float rinv = 1.f / (e0 + e1 + e2 + e3 + e4 + e5 + e6 + e7);
    float p_[8] = {e0 * rinv, e1 * rinv, e2 * rinv, e3 * rinv,
                   e4 * rinv, e5 * rinv, e6 * rinv, e7 * rinv};
    #pragma unroll
    for (int j = 0; j < 8; ++j) {
      pb[row * 8 + j] = p_[j];
      hb[row * 136 + 128 + j] = f2bf(p_[j]);
    }
  }
  __syncthreads();
  {  // SwiGLU scale + stage to hb
    const float b1x0 = b1[e * 64 + f15],      b1x1 = b1[e * 64 + 16 + f15];
    const float b1g0 = b1[e * 64 + 32 + f15], b1g1 = b1[e * 64 + 48 + f15];
    #pragma unroll
    for (int mf = 0; mf < 4; ++mf) {
      #pragma unroll
      for (int r = 0; r < 4; ++r) {
        int row = mf * 16 + fhi * 4 + r;
        float pe = pb[row * 8 + e];
        #pragma unroll
        for (int ci = 0; ci < 2; ++ci) {
          float xv = acc[mf][ci][r]     + (ci ? b1x1 : b1x0);
          float gv = acc[mf][ci + 2][r] + (ci ? b1g1 : b1g0);
          float av = pe * xv * gv / (1.f + __expf(-gv));  // pe * xp * silu(gate)
          hb[row * 136 + w * 32 + ci * 16 + f15] = f2bf(av);
        }
      }
    }
  }
  __syncthreads();
  {  // ACT write: this half's 16 act chunks (+ p/zero chunks from half 0)
    const int row = tid >> 2, q = tid & 3, key = row & 7;
    unsigned char* arow = ACT + (size_t)(m0 + row) * 640;
    const unsigned char* hrow = (const unsigned char*)(hb + row * 136);
    #pragma unroll
    for (int j = 0; j < 4; ++j) {
      int c = q + j * 4;            // 0..15
      int g = half * 16 + c;
      uint4 v = *(const uint4*)(hrow + c * 16);
      *(uint4*)(arow + (g >> 3) * 128 + (((g & 7) ^ key) << 4)) = v;
    }
    if (half == 0) {
      #pragma unroll
      for (int j = 0; j < 2; ++j) {
        int c = q + j * 4;          // 0..7 -> chunks 32..39
        int g = 32 + c;
        uint4 v = make_uint4(0, 0, 0, 0);
        if (c == 0) v = *(const uint4*)(hrow + 256);   // p (bf16 cols 128-135)
        *(uint4*)(arow + (g >> 3) * 128 + (((g & 7) ^ key) << 4)) = v;
      }
    }
  }
}

// ---------------- kernel 2: ACT @ W2s -> out ; zero-LDS, barrier-free K-loop ----------------
// grid 2048 = 256 m x 8 n; block 256 = 4 waves (2 mg x 2 ng), wave 64x64
__global__ __launch_bounds__(256, 3) void moe_gemm2(
    const unsigned char* __restrict__ ACT, const unsigned char* __restrict__ W2s,
    float* __restrict__ out) {
  __shared__ __align__(16) unsigned char smem[32768];  // epilogue slab f32[64][128]
  const int tid  = threadIdx.x;
  const int lane = tid & 63;
  const int w    = tid >> 6;
  const int mg   = w >> 1, ng = w & 1;
  const int f15  = lane & 15, fhi = lane >> 4;
  const int k7   = f15 & 7;

  const int wid = ((blockIdx.x & 7) << 8) + (blockIdx.x >> 3);  // 2048 = 8*256
  const int m0  = (wid >> 3) * 128;
  const int n0  = (wid & 7) * 128;

  f32x4 acc[4][4];
  #pragma unroll
  for (int a = 0; a < 4; ++a)
    #pragma unroll
    for (int b = 0; b < 4; ++b) acc[a][b] = f32x4{0.f, 0.f, 0.f, 0.f};

  const unsigned char* aB = ACT + (size_t)(m0 + mg * 64 + f15) * 640;
  const unsigned char* bB = W2s + (size_t)(n0 + ng * 64 + f15) * 640;
  const int ch0 = ((fhi)     ^ k7) << 4;
  const int ch1 = ((4 + fhi) ^ k7) << 4;

  #pragma unroll
  for (int kb = 0; kb < 5; ++kb) {
    bf16x8 a0[4], a1[4];
    #pragma unroll
    for (int mf = 0; mf < 4; ++mf) {
      const unsigned char* s_ = aB + mf * 10240 + kb * 128;
      a0[mf] = *(const bf16x8*)(s_ + ch0);
      a1[mf] = *(const bf16x8*)(s_ + ch1);
    }
    #pragma unroll
    for (int nf = 0; nf < 4; ++nf) {
      const unsigned char* s_ = bB + nf * 10240 + kb * 128;
      bf16x8 b0 = *(const bf16x8*)(s_ + ch0);
      bf16x8 b1v = *(const bf16x8*)(s_ + ch1);
      #pragma unroll
      for (int mf = 0; mf < 4; ++mf)
        acc[mf][nf] = __builtin_amdgcn_mfma_f32_16x16x32_bf16(a0[mf], b0, acc[mf][nf], 0, 0, 0);
      #pragma unroll
      for (int mf = 0; mf < 4; ++mf)
        acc[mf][nf] = __builtin_amdgcn_mfma_f32_16x16x32_bf16(a1[mf], b1v, acc[mf][nf], 0, 0, 0);
    }
  }

  // epilogue: two 64-row rounds through a swizzled f32 slab -> 512B coalesced stores
  float* slab = (float*)smem;
  #pragma unroll 1
  for (int q = 0; q < 2; ++q) {
    if (mg == q) {
      #pragma unroll
      for (int mf = 0; mf < 4; ++mf)
        #pragma unroll
        for (int nf = 0; nf < 4; ++nf)
          #pragma unroll
          for (int r = 0; r < 4; ++r) {
            int rl  = mf * 16 + fhi * 4 + r;
            int col = ng * 64 + nf * 16 + f15;
            slab[rl * 128 + (col ^ (((rl >> 2) & 7) << 2))] = acc[mf][nf][r];
          }
    }
    __syncthreads();
    #pragma unroll
    for (int j = 0; j < 8; ++j) {
      int rl = (tid >> 5) + j * 8;
      int c4 = tid & 31;
      f32x4 v = *(const f32x4*)(smem + rl * 512 + ((c4 ^ ((rl >> 2) & 7)) << 4));
      *(f32x4*)(out + (size_t)(m0 + q * 64 + rl) * 1024 + n0 + c4 * 4) = v;
    }
    __syncthreads();
  }
}

extern "C" void kernel_launch(void* const* d_in, const int* in_sizes, int n_in,
                              void* d_out, int out_size, void* d_ws, size_t ws_size,
                              hipStream_t stream) {
  const float* x  = (const float*)d_in[0];
  const float* Wr = (const float*)d_in[1];
  const float* br = (const float*)d_in[2];
  const float* W1 = (const float*)d_in[3];
  const float* b1 = (const float*)d_in[4];
  const float* W2 = (const float*)d_in[5];
  const float* b2 = (const float*)d_in[6];
  float* out = (float*)d_out;
  unsigned char* ws  = (unsigned char*)d_ws;
  unsigned char* B1s = ws;
  unsigned char* W2s = ws + W2S_OFF;
  unsigned char* ACT = ws + ACT_OFF;

  hipLaunchKernelGGL(prep_all, dim3(424), dim3(256), 0, stream, W1, Wr, W2, b2, B1s, W2s);
  hipLaunchKernelGGL(moe_gemm1, dim3(1024), dim3(256), 0, stream, x, br, b1, B1s, ACT);
  hipLaunchKernelGGL(moe_gemm2, dim3(2048), dim3(256), 0, stream, ACT, W2s, out);
}

// Round 12
// 165.581 us; speedup vs baseline: 1.7041x; 1.7041x over previous
//
#include <hip/hip_runtime.h>

typedef float f32x4 __attribute__((ext_vector_type(4)));
typedef short bf16x8 __attribute__((ext_vector_type(8)));

// ---- workspace layout (bytes) ----
// B1s: [16 kb][528 cols][128 B]  (bf16, chunk-swizzled; cols 512-519 router, 520-527 zero)
// W2s: [1024 cols][640 B]        (bf16, chunk-swizzled; rows 256-263 = b2, 264-319 zero)
// ACT: [32768 rows][640 B]       (bf16, chunk-swizzled; k 256-263 = p, 264-319 zero)
// xbf: [32768 rows][2048 B] bf16 chunk-swizzled — lives in d_out (consumed before gemm2 writes)
#define B1S_KBSZ 67584
#define W2S_OFF  1081344
#define ACT_OFF  1736704
// total ws required: 22,708,224 bytes

__device__ __forceinline__ unsigned short f2bf(float f) {
  unsigned int u = __float_as_uint(f);
  return (unsigned short)((u + 0x7FFFu + ((u >> 16) & 1u)) >> 16);
}
__device__ __forceinline__ unsigned int pack2(float a, float b) {
  return (unsigned int)f2bf(a) | ((unsigned int)f2bf(b) << 16);
}
__device__ __forceinline__ unsigned int cvtpk(float a, float b) {
  unsigned int r;
  asm("v_cvt_pk_bf16_f32 %0, %1, %2" : "=v"(r) : "v"(a), "v"(b));
  return r;
}

// ---------------- prep: pack [W1|Wr|0] -> B1s ; [W2;b2;0] -> W2s ----------------
__global__ __launch_bounds__(256) void prep_all(const float* __restrict__ W1,
                                                const float* __restrict__ Wr,
                                                const float* __restrict__ W2,
                                                const float* __restrict__ b2,
                                                unsigned char* __restrict__ B1s,
                                                unsigned char* __restrict__ W2s) {
  if (blockIdx.x < 264) {
    int t = blockIdx.x * 256 + threadIdx.x;
    int c   = t & 7;
    int col = (t >> 3) % 528;
    int kb  = (t >> 3) / 528;
    int e   = col >> 6;
    int hh  = col & 63;
    float v[8];
    #pragma unroll
    for (int jj = 0; jj < 8; ++jj) {
      int k = kb * 64 + c * 8 + jj;
      float f;
      if (col < 512)      f = W1[(e * 1024 + k) * 64 + hh];   // W1[e][k][hh]
      else if (col < 520) f = Wr[k * 8 + (col - 512)];        // Wr[k][e]
      else                f = 0.0f;
      v[jj] = f;
    }
    *(uint4*)(B1s + kb * B1S_KBSZ + col * 128 + ((c ^ (col & 7)) * 16)) =
        make_uint4(pack2(v[0], v[1]), pack2(v[2], v[3]), pack2(v[4], v[5]), pack2(v[6], v[7]));
  } else {
    int t = (blockIdx.x - 264) * 256 + threadIdx.x;
    int cj  = t % 40;
    int col = t / 40;
    float v[8];
    #pragma unroll
    for (int jj = 0; jj < 8; ++jj) {
      int k = cj * 8 + jj;
      float f;
      if (k < 256)      f = W2[k * 1024 + col];          // W2[e][h][c], k=e*32+h
      else if (k < 264) f = b2[(k - 256) * 1024 + col];  // b2[e][c]
      else              f = 0.0f;
      v[jj] = f;
    }
    int dstc = (cj & ~7) | ((cj & 7) ^ (col & 7));
    *(uint4*)(W2s + col * 640 + dstc * 16) =
        make_uint4(pack2(v[0], v[1]), pack2(v[2], v[3]), pack2(v[4], v[5]), pack2(v[6], v[7]));
  }
}

// ---------------- cvt: x f32 [32768][1024] -> xbf bf16 chunk-swizzled [32768][2048 B] ----------------
// pure streaming: 134 MB read + 67 MB write
__global__ __launch_bounds__(256) void cvt_x(const float* __restrict__ x,
                                             unsigned char* __restrict__ xbf) {
  int t = blockIdx.x * 256 + threadIdx.x;  // 4,194,304 threads
  int row = t >> 7, c = t & 127;
  const float* s = x + (size_t)row * 1024 + c * 8;
  f32x4 a = *(const f32x4*)s;
  f32x4 b = *(const f32x4*)(s + 4);
  uint4 u;
  u.x = cvtpk(a.x, a.y); u.y = cvtpk(a.z, a.w);
  u.z = cvtpk(b.x, b.y); u.w = cvtpk(b.z, b.w);
  *(uint4*)(xbf + (size_t)row * 2048 + (((c & ~7) | ((c & 7) ^ (row & 7))) << 4)) = u;
}

// ---------------- kernel 1: 64 rows x 4 experts/block, zero-LDS bf16 K-loop (gemm2-shaped) ----------------
// grid 1024 = 512 M-tiles x 2 halves; block 256 = 4 waves; wave = 1 expert (64x64)
// router: wave w accumulates router frag for ks in {4w..4w+3}; partials reduced in LDS
__global__ __launch_bounds__(256, 3) void moe_gemm1(
    const unsigned char* __restrict__ xbf, const float* __restrict__ br,
    const float* __restrict__ b1, const unsigned char* __restrict__ B1s,
    unsigned char* __restrict__ ACT) {
  __shared__ __align__(16) unsigned char smem[30720];
  // hb u16[64][136] @0 (17408) ; logitP f32[4][64][8] @17408 ; logit f32[64][8] @25600 ;
  // pb f32[64][8] @27648

  const int tid  = threadIdx.x;
  const int lane = tid & 63;
  const int w    = tid >> 6;   // wave 0..3
  const int f15  = lane & 15;
  const int fhi  = lane >> 4;
  const int k7   = f15 & 7;

  const int wid  = ((blockIdx.x & 7) << 7) + (blockIdx.x >> 3);  // XCD-chunked, 1024=8*128
  const int mt   = wid >> 1;
  const int half = wid & 1;
  const int m0   = mt << 6;
  const int e    = half * 4 + w;

  f32x4 acc[4][4];   // [mf][nf]
  f32x4 accR[4];     // router partial (this wave's 4 ks)
  #pragma unroll
  for (int a = 0; a < 4; ++a) {
    #pragma unroll
    for (int b = 0; b < 4; ++b) acc[a][b] = f32x4{0.f, 0.f, 0.f, 0.f};
    accR[a] = f32x4{0.f, 0.f, 0.f, 0.f};
  }

  // per-lane bases (all bf16, chunk-swizzled with key = row&7 = f15&7)
  const unsigned char* aB  = xbf + (size_t)(m0 + f15) * 2048;        // + mf*32768 + ks*128
  const unsigned char* bp  = B1s + (size_t)(e * 64 + f15) * 128;     // + kso + i*2048
  const unsigned char* brt = B1s + (size_t)(512 + f15) * 128;        // + kso
  const int ch0 = ((fhi)     ^ k7) << 4;
  const int ch1 = ((4 + fhi) ^ k7) << 4;

  #pragma unroll
  for (int ks = 0; ks < 16; ++ks) {
    const size_t kso = (size_t)ks * B1S_KBSZ;
    const bool doR = ((ks >> 2) == w);
    bf16x8 a0[4], a1[4];
    #pragma unroll
    for (int mf = 0; mf < 4; ++mf) {
      const unsigned char* s_ = aB + mf * 32768 + ks * 128;
      a0[mf] = *(const bf16x8*)(s_ + ch0);
      a1[mf] = *(const bf16x8*)(s_ + ch1);
    }
    #pragma unroll
    for (int i = 0; i < 4; ++i) {
      const unsigned char* s_ = bp + kso + i * 2048;
      bf16x8 b0  = *(const bf16x8*)(s_ + ch0);
      bf16x8 b1v = *(const bf16x8*)(s_ + ch1);
      #pragma unroll
      for (int mf = 0; mf < 4; ++mf)
        acc[mf][i] = __builtin_amdgcn_mfma_f32_16x16x32_bf16(a0[mf], b0, acc[mf][i], 0, 0, 0);
      #pragma unroll
      for (int mf = 0; mf < 4; ++mf)
        acc[mf][i] = __builtin_amdgcn_mfma_f32_16x16x32_bf16(a1[mf], b1v, acc[mf][i], 0, 0, 0);
    }
    if (doR) {
      bf16x8 r0 = *(const bf16x8*)(brt + kso + ch0);
      bf16x8 r1 = *(const bf16x8*)(brt + kso + ch1);
      #pragma unroll
      for (int mf = 0; mf < 4; ++mf)
        accR[mf] = __builtin_amdgcn_mfma_f32_16x16x32_bf16(a0[mf], r0, accR[mf], 0, 0, 0);
      #pragma unroll
      for (int mf = 0; mf < 4; ++mf)
        accR[mf] = __builtin_amdgcn_mfma_f32_16x16x32_bf16(a1[mf], r1, accR[mf], 0, 0, 0);
    }
    if ((ks & 3) == 3) __syncthreads();  // keep waves converged for L1 A-sharing
  }

  unsigned short* hb = (unsigned short*)smem;      // [64][136]: cols 0-127 act, 128-135 p(bf16)
  float* logitP = (float*)(smem + 17408);          // [4][64][8]
  float* logit  = (float*)(smem + 25600);          // [64][8]
  float* pb     = (float*)(smem + 27648);          // [64][8]

  if (f15 < 8) {  // router partials
    #pragma unroll
    for (int mf = 0; mf < 4; ++mf)
      #pragma unroll
      for (int r = 0; r < 4; ++r)
        logitP[(w * 64 + mf * 16 + fhi * 4 + r) * 8 + f15] = accR[mf][r];
  }
  __syncthreads();
  {  // reduce partials + br
    int row = tid >> 2, ep = tid & 3;
    #pragma unroll
    for (int j = 0; j < 2; ++j) {
      int ee = ep * 2 + j;
      float s = logitP[row * 8 + ee] + logitP[(64 + row) * 8 + ee] +
                logitP[(128 + row) * 8 + ee] + logitP[(192 + row) * 8 + ee];
      logit[row * 8 + ee] = s + br[ee];
    }
  }
  __syncthreads();
  if (tid < 64) {  // per-row softmax
    int row = tid;
    const float* lg = logit + row * 8;
    float l0 = lg[0], l1 = lg[1], l2 = lg[2], l3 = lg[3];
    float l4 = lg[4], l5 = lg[5], l6 = lg[6], l7 = lg[7];
    float mx = fmaxf(fmaxf(fmaxf(l0, l1), fmaxf(l2, l3)),
                     fmaxf(fmaxf(l4, l5), fmaxf(l6, l7)));
    float e0 = __expf(l0 - mx), e1 = __expf(l1 - mx), e2 = __expf(l2 - mx), e3 = __expf(l3 - mx);
    float e4 = __expf(l4 - mx), e5 = __expf(l5 - mx), e6 = __expf(l6 - mx), e7 = __expf(l7 - mx);
    float rinv = 1.f / (e0 + e1 + e2 + e3 + e4 + e5 + e6 + e7);
    float p_[8] = {e0 * rinv, e1 * rinv, e2 * rinv, e3 * rinv,
                   e4 * rinv, e5 * rinv, e6 * rinv, e7 * rinv};
    #pragma unroll
    for (int j = 0; j < 8; ++j) {
      pb[row * 8 + j] = p_[j];
      hb[row * 136 + 128 + j] = f2bf(p_[j]);
    }
  }
  __syncthreads();
  {  // SwiGLU scale + stage to hb
    const float b1x0 = b1[e * 64 + f15],      b1x1 = b1[e * 64 + 16 + f15];
    const float b1g0 = b1[e * 64 + 32 + f15], b1g1 = b1[e * 64 + 48 + f15];
    #pragma unroll
    for (int mf = 0; mf < 4; ++mf) {
      #pragma unroll
      for (int r = 0; r < 4; ++r) {
        int row = mf * 16 + fhi * 4 + r;
        float pe = pb[row * 8 + e];
        #pragma unroll
        for (int ci = 0; ci < 2; ++ci) {
          float xv = acc[mf][ci][r]     + (ci ? b1x1 : b1x0);
          float gv = acc[mf][ci + 2][r] + (ci ? b1g1 : b1g0);
          float av = pe * xv * gv / (1.f + __expf(-gv));  // pe * xp * silu(gate)
          hb[row * 136 + w * 32 + ci * 16 + f15] = f2bf(av);
        }
      }
    }
  }
  __syncthreads();
  {  // ACT write: this half's 16 act chunks (+ p/zero chunks from half 0)
    const int row = tid >> 2, q = tid & 3, key = row & 7;
    unsigned char* arow = ACT + (size_t)(m0 + row) * 640;
    const unsigned char* hrow = (const unsigned char*)(hb + row * 136);
    #pragma unroll
    for (int j = 0; j < 4; ++j) {
      int c = q + j * 4;            // 0..15
      int g = half * 16 + c;
      uint4 v = *(const uint4*)(hrow + c * 16);
      *(uint4*)(arow + (g >> 3) * 128 + (((g & 7) ^ key) << 4)) = v;
    }
    if (half == 0) {
      #pragma unroll
      for (int j = 0; j < 2; ++j) {
        int c = q + j * 4;          // 0..7 -> chunks 32..39
        int g = 32 + c;
        uint4 v = make_uint4(0, 0, 0, 0);
        if (c == 0) v = *(const uint4*)(hrow + 256);   // p (bf16 cols 128-135)
        *(uint4*)(arow + (g >> 3) * 128 + (((g & 7) ^ key) << 4)) = v;
      }
    }
  }
}

// ---------------- kernel 2: ACT @ W2s -> out ; zero-LDS, barrier-free K-loop ----------------
// grid 2048 = 256 m x 8 n; block 256 = 4 waves (2 mg x 2 ng), wave 64x64
__global__ __launch_bounds__(256, 3) void moe_gemm2(
    const unsigned char* __restrict__ ACT, const unsigned char* __restrict__ W2s,
    float* __restrict__ out) {
  __shared__ __align__(16) unsigned char smem[32768];  // epilogue slab f32[64][128]
  const int tid  = threadIdx.x;
  const int lane = tid & 63;
  const int w    = tid >> 6;
  const int mg   = w >> 1, ng = w & 1;
  const int f15  = lane & 15, fhi = lane >> 4;
  const int k7   = f15 & 7;

  const int wid = ((blockIdx.x & 7) << 8) + (blockIdx.x >> 3);  // 2048 = 8*256
  const int m0  = (wid >> 3) * 128;
  const int n0  = (wid & 7) * 128;

  f32x4 acc[4][4];
  #pragma unroll
  for (int a = 0; a < 4; ++a)
    #pragma unroll
    for (int b = 0; b < 4; ++b) acc[a][b] = f32x4{0.f, 0.f, 0.f, 0.f};

  const unsigned char* aB = ACT + (size_t)(m0 + mg * 64 + f15) * 640;
  const unsigned char* bB = W2s + (size_t)(n0 + ng * 64 + f15) * 640;
  const int ch0 = ((fhi)     ^ k7) << 4;
  const int ch1 = ((4 + fhi) ^ k7) << 4;

  #pragma unroll
  for (int kb = 0; kb < 5; ++kb) {
    bf16x8 a0[4], a1[4];
    #pragma unroll
    for (int mf = 0; mf < 4; ++mf) {
      const unsigned char* s_ = aB + mf * 10240 + kb * 128;
      a0[mf] = *(const bf16x8*)(s_ + ch0);
      a1[mf] = *(const bf16x8*)(s_ + ch1);
    }
    #pragma unroll
    for (int nf = 0; nf < 4; ++nf) {
      const unsigned char* s_ = bB + nf * 10240 + kb * 128;
      bf16x8 b0 = *(const bf16x8*)(s_ + ch0);
      bf16x8 b1v = *(const bf16x8*)(s_ + ch1);
      #pragma unroll
      for (int mf = 0; mf < 4; ++mf)
        acc[mf][nf] = __builtin_amdgcn_mfma_f32_16x16x32_bf16(a0[mf], b0, acc[mf][nf], 0, 0, 0);
      #pragma unroll
      for (int mf = 0; mf < 4; ++mf)
        acc[mf][nf] = __builtin_amdgcn_mfma_f32_16x16x32_bf16(a1[mf], b1v, acc[mf][nf], 0, 0, 0);
    }
  }

  // epilogue: two 64-row rounds through a swizzled f32 slab -> 512B coalesced stores
  float* slab = (float*)smem;
  #pragma unroll 1
  for (int q = 0; q < 2; ++q) {
    if (mg == q) {
      #pragma unroll
      for (int mf = 0; mf < 4; ++mf)
        #pragma unroll
        for (int nf = 0; nf < 4; ++nf)
          #pragma unroll
          for (int r = 0; r < 4; ++r) {
            int rl  = mf * 16 + fhi * 4 + r;
            int col = ng * 64 + nf * 16 + f15;
            slab[rl * 128 + (col ^ (((rl >> 2) & 7) << 2))] = acc[mf][nf][r];
          }
    }
    __syncthreads();
    #pragma unroll
    for (int j = 0; j < 8; ++j) {
      int rl = (tid >> 5) + j * 8;
      int c4 = tid & 31;
      f32x4 v = *(const f32x4*)(smem + rl * 512 + ((c4 ^ ((rl >> 2) & 7)) << 4));
      *(f32x4*)(out + (size_t)(m0 + q * 64 + rl) * 1024 + n0 + c4 * 4) = v;
    }
    __syncthreads();
  }
}

extern "C" void kernel_launch(void* const* d_in, const int* in_sizes, int n_in,
                              void* d_out, int out_size, void* d_ws, size_t ws_size,
                              hipStream_t stream) {
  const float* x  = (const float*)d_in[0];
  const float* Wr = (const float*)d_in[1];
  const float* br = (const float*)d_in[2];
  const float* W1 = (const float*)d_in[3];
  const float* b1 = (const float*)d_in[4];
  const float* W2 = (const float*)d_in[5];
  const float* b2 = (const float*)d_in[6];
  float* out = (float*)d_out;
  unsigned char* ws  = (unsigned char*)d_ws;
  unsigned char* B1s = ws;
  unsigned char* W2s = ws + W2S_OFF;
  unsigned char* ACT = ws + ACT_OFF;
  unsigned char* xbf = (unsigned char*)d_out;  // 67 MB scratch inside the 134 MB output buffer;
                                               // consumed by gemm1 before gemm2 overwrites d_out

  hipLaunchKernelGGL(prep_all, dim3(424), dim3(256), 0, stream, W1, Wr, W2, b2, B1s, W2s);
  hipLaunchKernelGGL(cvt_x, dim3(16384), dim3(256), 0, stream, x, xbf);
  hipLaunchKernelGGL(moe_gemm1, dim3(1024), dim3(256), 0, stream, xbf, br, b1, B1s, ACT);
  hipLaunchKernelGGL(moe_gemm2, dim3(2048), dim3(256), 0, stream, ACT, W2s, out);
}